// Round 1
// baseline (316.188 us; speedup 1.0000x reference)
//
#include <hip/hip_runtime.h>
#include <math.h>

#define T_SEQ 2048
#define NH    32
#define NKV   8
#define HS    128
#define FD    64
#define WB    64
#define NBLK  32          // T_SEQ / WB
#define EPSF  1e-12f
#define NEGINF -3.0e38f

// ws layout (floats):
//  fq : [NH][NBLK][128][64]   transposed tiles (f-major)   = 8,388,608
//  fk : [NH][T][128]          row-major                    = 8,388,608
//  S  : [NH][NBLK][128][128]  partial->prefix states       = 16,777,216
//  zs : [NH][NBLK][128]       zsum partial->prefix         = 131,072
#define WS_FQ 0
#define WS_FK 8388608
#define WS_S  16777216
#define WS_ZS 33554432

// ---------------- K1: feature maps f_q, f_k ----------------
// grid (NBLK, NH, 2), block 256.  z = W^T x ; out = [softmax(z), softmax(-z)] clipped.
__global__ __launch_bounds__(256) void k_fmap(
    const float* __restrict__ qg, const float* __restrict__ kg,
    const float* __restrict__ wq, const float* __restrict__ wk,
    float* __restrict__ fq, float* __restrict__ fk)
{
  __shared__ float sX[WB * HS];   // [r][d] row-major
  __shared__ float sW[HS * FD];   // [d][f]
  const int lt = blockIdx.x, h = blockIdx.y, isk = blockIdx.z;
  const int tid = threadIdx.x;

  const float* xbase = isk ? (kg + (h >> 2) * HS) : (qg + h * HS);
  const int    xstr  = isk ? (NKV * HS) : (NH * HS);
  for (int idx = tid * 4; idx < WB * HS; idx += 1024) {
    int r = idx >> 7, c = idx & (HS - 1);
    *(float4*)(sX + idx) = *(const float4*)(xbase + (size_t)(lt * WB + r) * xstr + c);
  }
  const float* wb = (isk ? wk : wq) + (size_t)h * HS * FD;
  for (int idx = tid * 4; idx < HS * FD; idx += 1024)
    *(float4*)(sW + idx) = *(const float4*)(wb + idx);
  __syncthreads();

  const int ty = tid >> 4, tx = tid & 15;   // rows ty*4.., feats tx*4..
  float z[4][4];
#pragma unroll
  for (int i = 0; i < 4; ++i) { z[i][0] = 0.f; z[i][1] = 0.f; z[i][2] = 0.f; z[i][3] = 0.f; }

  for (int d = 0; d < HS; d += 4) {
    float av[4][4], bv[4][4];
#pragma unroll
    for (int i = 0; i < 4; ++i) {
      float4 a = *(const float4*)(sX + (ty * 4 + i) * HS + d);
      av[i][0] = a.x; av[i][1] = a.y; av[i][2] = a.z; av[i][3] = a.w;
    }
#pragma unroll
    for (int j = 0; j < 4; ++j) {
      float4 b = *(const float4*)(sW + (d + j) * FD + tx * 4);
      bv[j][0] = b.x; bv[j][1] = b.y; bv[j][2] = b.z; bv[j][3] = b.w;
    }
#pragma unroll
    for (int i = 0; i < 4; ++i)
#pragma unroll
      for (int j = 0; j < 4; ++j)
#pragma unroll
        for (int f = 0; f < 4; ++f) z[i][f] += av[i][j] * bv[j][f];
  }

  float E1[4][4], E2[4][4];
#pragma unroll
  for (int i = 0; i < 4; ++i) {
    float mx = fmaxf(fmaxf(z[i][0], z[i][1]), fmaxf(z[i][2], z[i][3]));
    float mn = fminf(fminf(z[i][0], z[i][1]), fminf(z[i][2], z[i][3]));
#pragma unroll
    for (int o = 1; o < 16; o <<= 1) {
      mx = fmaxf(mx, __shfl_xor(mx, o));
      mn = fminf(mn, __shfl_xor(mn, o));
    }
    float s1 = 0.f, s2 = 0.f;
#pragma unroll
    for (int j = 0; j < 4; ++j) {
      E1[i][j] = expf(z[i][j] - mx); s1 += E1[i][j];
      E2[i][j] = expf(mn - z[i][j]); s2 += E2[i][j];
    }
#pragma unroll
    for (int o = 1; o < 16; o <<= 1) { s1 += __shfl_xor(s1, o); s2 += __shfl_xor(s2, o); }
    float r1 = 1.f / s1, r2 = 1.f / s2;
#pragma unroll
    for (int j = 0; j < 4; ++j) {
      E1[i][j] = fmaxf(E1[i][j] * r1, EPSF);
      E2[i][j] = fmaxf(E2[i][j] * r2, EPSF);
    }
  }

  if (!isk) {
    // transposed tile: [f 0..127][r 0..63]
    float* ob = fq + (((size_t)(h * NBLK + lt)) << 13);
#pragma unroll
    for (int j = 0; j < 4; ++j) {
      int f = tx * 4 + j;
      *(float4*)(ob + f * 64 + ty * 4)        = make_float4(E1[0][j], E1[1][j], E1[2][j], E1[3][j]);
      *(float4*)(ob + (f + FD) * 64 + ty * 4) = make_float4(E2[0][j], E2[1][j], E2[2][j], E2[3][j]);
    }
  } else {
    // row-major [l][f 0..127]
#pragma unroll
    for (int i = 0; i < 4; ++i) {
      float* ob = fk + ((size_t)h * T_SEQ + lt * WB + ty * 4 + i) * (2 * FD);
      *(float4*)(ob + tx * 4)      = make_float4(E1[i][0], E1[i][1], E1[i][2], E1[i][3]);
      *(float4*)(ob + FD + tx * 4) = make_float4(E2[i][0], E2[i][1], E2[i][2], E2[i][3]);
    }
  }
}

// ---------------- K2: per-block partial states ----------------
// grid (NBLK, NH), block 256.  S_b[f][d] = sum_j fk[j][f] * v[j][d]; zs_b[f] = sum_j fk[j][f]
__global__ __launch_bounds__(256) void k_state(
    const float* __restrict__ fk, const float* __restrict__ vg,
    float* __restrict__ S, float* __restrict__ zs)
{
  __shared__ float sA[WB * 128];  // fk [j][f]
  __shared__ float sB[WB * HS];   // v  [j][d]
  const int b = blockIdx.x, h = blockIdx.y, tid = threadIdx.x;

  for (int idx = tid * 4; idx < WB * 128; idx += 1024)
    *(float4*)(sA + idx) = *(const float4*)(fk + ((size_t)h * T_SEQ + b * WB) * 128 + idx);
  for (int idx = tid * 4; idx < WB * HS; idx += 1024) {
    int r = idx >> 7, c = idx & (HS - 1);
    *(float4*)(sB + idx) = *(const float4*)(vg + (size_t)(b * WB + r) * (NKV * HS) + (h >> 2) * HS + c);
  }
  __syncthreads();

  const int ty = tid >> 4, tx = tid & 15;   // f rows ty*8.., d cols tx*8..
  float acc[8][8];
#pragma unroll
  for (int i = 0; i < 8; ++i)
#pragma unroll
    for (int j = 0; j < 8; ++j) acc[i][j] = 0.f;

  for (int j = 0; j < WB; ++j) {
    float4 a0 = *(const float4*)(sA + j * 128 + ty * 8);
    float4 a1 = *(const float4*)(sA + j * 128 + ty * 8 + 4);
    float4 b0 = *(const float4*)(sB + j * HS + tx * 8);
    float4 b1 = *(const float4*)(sB + j * HS + tx * 8 + 4);
    float av[8] = {a0.x, a0.y, a0.z, a0.w, a1.x, a1.y, a1.z, a1.w};
    float bv[8] = {b0.x, b0.y, b0.z, b0.w, b1.x, b1.y, b1.z, b1.w};
#pragma unroll
    for (int i = 0; i < 8; ++i)
#pragma unroll
      for (int c = 0; c < 8; ++c) acc[i][c] += av[i] * bv[c];
  }

  float* Sb = S + (((size_t)(h * NBLK + b)) << 14);
#pragma unroll
  for (int i = 0; i < 8; ++i) {
    *(float4*)(Sb + (ty * 8 + i) * HS + tx * 8)     = make_float4(acc[i][0], acc[i][1], acc[i][2], acc[i][3]);
    *(float4*)(Sb + (ty * 8 + i) * HS + tx * 8 + 4) = make_float4(acc[i][4], acc[i][5], acc[i][6], acc[i][7]);
  }
  if (tid < 128) {
    float s = 0.f;
    for (int j = 0; j < WB; ++j) s += sA[j * 128 + tid];
    zs[((size_t)(h * NBLK + b)) * 128 + tid] = s;
  }
}

// ---------------- K3: inclusive prefix over blocks ----------------
// grid (65, NH), block 256
__global__ __launch_bounds__(256) void k_prefix(float* __restrict__ S, float* __restrict__ zs)
{
  const int h = blockIdx.y;
  const int e = blockIdx.x * 256 + threadIdx.x;
  if (e < 16384) {
    float acc = 0.f;
    float* p = S + ((size_t)h * NBLK << 14) + e;
    for (int b = 0; b < NBLK; ++b) { acc += p[(size_t)b << 14]; p[(size_t)b << 14] = acc; }
  } else if (e < 16512) {
    int f = e - 16384;
    float acc = 0.f;
    float* p = zs + (size_t)h * NBLK * 128 + f;
    for (int b = 0; b < NBLK; ++b) { acc += p[b * 128]; p[b * 128] = acc; }
  }
}

// ---------------- K4: main attention ----------------
// grid (NBLK, NH), block 256
__global__ __launch_bounds__(256) void k_main(
    const float* __restrict__ qg, const float* __restrict__ kg, const float* __restrict__ vg,
    const float* __restrict__ fq, const float* __restrict__ Sc, const float* __restrict__ zc,
    const float* __restrict__ wfac, float* __restrict__ out)
{
  __shared__ float R1[8192];   // fq^T tile -> Q^T -> P^T
  __shared__ float R2[8192];   // S half -> K^T half -> V half
  const int B = blockIdx.x, h = blockIdx.y;
  const int tid = threadIdx.x;
  const int ty = tid >> 4, tx = tid & 15;
  const int lane = tid & 63, wv = tid >> 6;

  float y[4][8];
#pragma unroll
  for (int i = 0; i < 4; ++i)
#pragma unroll
    for (int j = 0; j < 8; ++j) y[i][j] = 0.f;
  float sln[4] = {0.f, 0.f, 0.f, 0.f};

  // ---- linear part: y += fq^T tile (A, K-major) x S_cum[B-2] ----
  if (B >= 2) {
    const float* fqt = fq + (((size_t)(h * NBLK + B)) << 13);
    for (int idx = tid * 4; idx < 8192; idx += 1024)
      *(float4*)(R1 + idx) = *(const float4*)(fqt + idx);
    const float* Sb = Sc + (((size_t)(h * NBLK + (B - 2))) << 14);
    const float* zb = zc + (size_t)(h * NBLK + (B - 2)) * 128;
#pragma unroll
    for (int half = 0; half < 2; ++half) {
      for (int idx = tid * 4; idx < 8192; idx += 1024)
        *(float4*)(R2 + idx) = *(const float4*)(Sb + half * 8192 + idx);
      __syncthreads();
      const float* Ab = R1 + (half * 64) * 64;
      for (int kk = 0; kk < 64; ++kk) {
        float4 a  = *(const float4*)(Ab + kk * 64 + ty * 4);
        float4 b0 = *(const float4*)(R2 + kk * HS + tx * 8);
        float4 b1 = *(const float4*)(R2 + kk * HS + tx * 8 + 4);
        float zkk = zb[half * 64 + kk];
        float av[4] = {a.x, a.y, a.z, a.w};
        float bv[8] = {b0.x, b0.y, b0.z, b0.w, b1.x, b1.y, b1.z, b1.w};
#pragma unroll
        for (int i = 0; i < 4; ++i) {
          sln[i] += av[i] * zkk;
#pragma unroll
          for (int c = 0; c < 8; ++c) y[i][c] += av[i] * bv[c];
        }
      }
      __syncthreads();
    }
  }

  // ---- stage Q^T into R1 (transpose-on-load) ----
  __syncthreads();
  {
    const float* qrow = qg + (size_t)(B * WB + lane) * (NH * HS) + h * HS;
#pragma unroll
    for (int it = 0; it < 8; ++it) {
      int d0 = wv * 4 + it * 16;
      float4 x = *(const float4*)(qrow + d0);
      R1[(d0 + 0) * 64 + lane] = x.x;
      R1[(d0 + 1) * 64 + lane] = x.y;
      R1[(d0 + 2) * 64 + lane] = x.z;
      R1[(d0 + 3) * 64 + lane] = x.w;
    }
  }

  const int nh_ = (B >= 1) ? 2 : 1;
  const int kb0 = B - (nh_ - 1);
  float p[2][4][4];

  // ---- scores: per key half, stage K^T and GEMM (K=128) ----
#pragma unroll
  for (int hf = 0; hf < 2; ++hf) {
    if (hf >= nh_) continue;
    {
      const float* krow = kg + (size_t)((kb0 + hf) * WB + lane) * (NKV * HS) + (h >> 2) * HS;
#pragma unroll
      for (int it = 0; it < 8; ++it) {
        int d0 = wv * 4 + it * 16;
        float4 x = *(const float4*)(krow + d0);
        R2[(d0 + 0) * 64 + lane] = x.x;
        R2[(d0 + 1) * 64 + lane] = x.y;
        R2[(d0 + 2) * 64 + lane] = x.z;
        R2[(d0 + 3) * 64 + lane] = x.w;
      }
    }
    __syncthreads();
#pragma unroll
    for (int i = 0; i < 4; ++i) { p[hf][i][0] = 0.f; p[hf][i][1] = 0.f; p[hf][i][2] = 0.f; p[hf][i][3] = 0.f; }
    for (int d = 0; d < HS; d += 4) {
#pragma unroll
      for (int j = 0; j < 4; ++j) {
        float4 a = *(const float4*)(R1 + (d + j) * 64 + ty * 4);
        float4 b = *(const float4*)(R2 + (d + j) * 64 + tx * 4);
        float av[4] = {a.x, a.y, a.z, a.w};
        float bv[4] = {b.x, b.y, b.z, b.w};
#pragma unroll
        for (int i = 0; i < 4; ++i)
#pragma unroll
          for (int c = 0; c < 4; ++c) p[hf][i][c] += av[i] * bv[c];
      }
    }
    __syncthreads();
  }

  // ---- masked softmax over (up to) 128 cols, exact row max ----
  const float scale = 0.088388347648318447f;   // 128^-0.5
  float wf = wfac[h];
  wf = 1.f / (1.f + expf(-wf));
  float ssum[4];
#pragma unroll
  for (int i = 0; i < 4; ++i) {
    const int rrow = ty * 4 + i;
    float m = NEGINF;
#pragma unroll
    for (int hf = 0; hf < 2; ++hf) {
      if (hf >= nh_) continue;
      const bool causal = (hf == nh_ - 1);
#pragma unroll
      for (int j = 0; j < 4; ++j) {
        float s = p[hf][i][j] * scale;
        if (causal && (tx * 4 + j > rrow)) s = NEGINF;
        p[hf][i][j] = s;
        m = fmaxf(m, s);
      }
    }
#pragma unroll
    for (int o = 1; o < 16; o <<= 1) m = fmaxf(m, __shfl_xor(m, o));
    float ss = 0.f;
#pragma unroll
    for (int hf = 0; hf < 2; ++hf) {
      if (hf >= nh_) continue;
#pragma unroll
      for (int j = 0; j < 4; ++j) {
        float e = (p[hf][i][j] > -1.0e38f) ? wf * expf(p[hf][i][j] - m) : 0.f;
        p[hf][i][j] = e;
        ss += e;
      }
    }
#pragma unroll
    for (int o = 1; o < 16; o <<= 1) ss += __shfl_xor(ss, o);
    ssum[i] = ss;
  }

  // ---- write P^T (K-major) into R1 ----
#pragma unroll
  for (int hf = 0; hf < 2; ++hf) {
    if (hf >= nh_) continue;
#pragma unroll
    for (int j = 0; j < 4; ++j) {
      int jj = hf * 64 + tx * 4 + j;
      *(float4*)(R1 + jj * 64 + ty * 4) = make_float4(p[hf][0][j], p[hf][1][j], p[hf][2][j], p[hf][3][j]);
    }
  }

  // ---- PV: per half, stage V and GEMM (K=64 each) ----
#pragma unroll
  for (int hf = 0; hf < 2; ++hf) {
    if (hf >= nh_) continue;
    for (int idx = tid * 4; idx < WB * HS; idx += 1024) {
      int rr = idx >> 7, cc = idx & (HS - 1);
      *(float4*)(R2 + idx) = *(const float4*)(vg + (size_t)((kb0 + hf) * WB + rr) * (NKV * HS) + (h >> 2) * HS + cc);
    }
    __syncthreads();
    const float* Ab = R1 + hf * 64 * 64;
    for (int kk = 0; kk < WB; ++kk) {
      float4 a  = *(const float4*)(Ab + kk * 64 + ty * 4);
      float4 b0 = *(const float4*)(R2 + kk * HS + tx * 8);
      float4 b1 = *(const float4*)(R2 + kk * HS + tx * 8 + 4);
      float av[4] = {a.x, a.y, a.z, a.w};
      float bv[8] = {b0.x, b0.y, b0.z, b0.w, b1.x, b1.y, b1.z, b1.w};
#pragma unroll
      for (int i = 0; i < 4; ++i)
#pragma unroll
        for (int c = 0; c < 8; ++c) y[i][c] += av[i] * bv[c];
    }
    __syncthreads();
  }

  // ---- epilogue ----
  const size_t obase = ((size_t)h * T_SEQ + B * WB) * HS;
#pragma unroll
  for (int i = 0; i < 4; ++i) {
    float inv = 1.f / (ssum[i] + sln[i]);
    int rrow = ty * 4 + i;
    *(float4*)(out + obase + rrow * HS + tx * 8)     =
        make_float4(y[i][0] * inv, y[i][1] * inv, y[i][2] * inv, y[i][3] * inv);
    *(float4*)(out + obase + rrow * HS + tx * 8 + 4) =
        make_float4(y[i][4] * inv, y[i][5] * inv, y[i][6] * inv, y[i][7] * inv);
  }
}

extern "C" void kernel_launch(void* const* d_in, const int* in_sizes, int n_in,
                              void* d_out, int out_size, void* d_ws, size_t ws_size,
                              hipStream_t stream) {
  const float* q    = (const float*)d_in[0];
  const float* k    = (const float*)d_in[1];
  const float* v    = (const float*)d_in[2];
  const float* wq   = (const float*)d_in[3];
  const float* wk   = (const float*)d_in[4];
  const float* wfac = (const float*)d_in[5];
  float* out = (float*)d_out;
  float* ws  = (float*)d_ws;

  float* fq = ws + WS_FQ;
  float* fk = ws + WS_FK;
  float* S  = ws + WS_S;
  float* zs = ws + WS_ZS;

  k_fmap<<<dim3(NBLK, NH, 2), 256, 0, stream>>>(q, k, wq, wk, fq, fk);
  k_state<<<dim3(NBLK, NH), 256, 0, stream>>>(fk, v, S, zs);
  k_prefix<<<dim3(65, NH), 256, 0, stream>>>(S, zs);
  k_main<<<dim3(NBLK, NH), 256, 0, stream>>>(q, k, v, fq, S, zs, wfac, out);
}

// Round 2
// 232.844 us; speedup vs baseline: 1.3579x; 1.3579x over previous
//
#include <hip/hip_runtime.h>
#include <math.h>

#define T_SEQ 2048
#define NH    32
#define NKV   8
#define HS    128
#define FD    64
#define NBLK  32          // T_SEQ / 64
#define EPSF  1e-12f
#define LDP   136         // LDS row pitch in bf16 elems (16B aligned, bank-skewed)

typedef unsigned short u16;
typedef __bf16 bf16x8 __attribute__((ext_vector_type(8)));
typedef float  f32x4  __attribute__((ext_vector_type(4)));

__device__ __forceinline__ u16 f2b(float f) {
  unsigned u = __builtin_bit_cast(unsigned, f);
  return (u16)((u + 0x7fffu + ((u >> 16) & 1u)) >> 16);
}
__device__ __forceinline__ float b2f(u16 b) {
  unsigned u = ((unsigned)b) << 16;
  return __builtin_bit_cast(float, u);
}

// ws layout (bytes):
//  fqb: bf16 [NH][NBLK][64 q][128 f]          16,777,216
//  fk : f32  [NH][T][128]                     33,554,432
//  ST : bf16 [NH][NBLK][144 d][128 f]         37,748,736   (row128=z, 129..143=0)
//  VT : bf16 [NKV][128 d][T key]               4,194,304
#define FQB_OFF 0
#define FK_OFF  16777216
#define ST_OFF  50331648
#define VT_OFF  88080384

// ---------------- K1: feature maps ----------------
__global__ __launch_bounds__(256) void k_fmap(
    const float* __restrict__ qg, const float* __restrict__ kg,
    const float* __restrict__ wq, const float* __restrict__ wk,
    u16* __restrict__ fqb, float* __restrict__ fk)
{
  __shared__ float sX[64 * HS];
  __shared__ float sW[HS * FD];
  const int lt = blockIdx.x, h = blockIdx.y, isk = blockIdx.z;
  const int tid = threadIdx.x;

  const float* xbase = isk ? (kg + (h >> 2) * HS) : (qg + h * HS);
  const int    xstr  = isk ? (NKV * HS) : (NH * HS);
  for (int idx = tid * 4; idx < 64 * HS; idx += 1024) {
    int r = idx >> 7, c = idx & (HS - 1);
    *(float4*)(sX + idx) = *(const float4*)(xbase + (size_t)(lt * 64 + r) * xstr + c);
  }
  const float* wb = (isk ? wk : wq) + (size_t)h * HS * FD;
  for (int idx = tid * 4; idx < HS * FD; idx += 1024)
    *(float4*)(sW + idx) = *(const float4*)(wb + idx);
  __syncthreads();

  const int ty = tid >> 4, tx = tid & 15;
  float z[4][4];
#pragma unroll
  for (int i = 0; i < 4; ++i) { z[i][0] = 0.f; z[i][1] = 0.f; z[i][2] = 0.f; z[i][3] = 0.f; }

  for (int d = 0; d < HS; d += 4) {
    float av[4][4], bv[4][4];
#pragma unroll
    for (int i = 0; i < 4; ++i) {
      float4 a = *(const float4*)(sX + (ty * 4 + i) * HS + d);
      av[i][0] = a.x; av[i][1] = a.y; av[i][2] = a.z; av[i][3] = a.w;
    }
#pragma unroll
    for (int j = 0; j < 4; ++j) {
      float4 b = *(const float4*)(sW + (d + j) * FD + tx * 4);
      bv[j][0] = b.x; bv[j][1] = b.y; bv[j][2] = b.z; bv[j][3] = b.w;
    }
#pragma unroll
    for (int i = 0; i < 4; ++i)
#pragma unroll
      for (int j = 0; j < 4; ++j)
#pragma unroll
        for (int f = 0; f < 4; ++f) z[i][f] += av[i][j] * bv[j][f];
  }

  float E1[4][4], E2[4][4];
#pragma unroll
  for (int i = 0; i < 4; ++i) {
    float mx = fmaxf(fmaxf(z[i][0], z[i][1]), fmaxf(z[i][2], z[i][3]));
    float mn = fminf(fminf(z[i][0], z[i][1]), fminf(z[i][2], z[i][3]));
#pragma unroll
    for (int o = 1; o < 16; o <<= 1) {
      mx = fmaxf(mx, __shfl_xor(mx, o));
      mn = fminf(mn, __shfl_xor(mn, o));
    }
    float s1 = 0.f, s2 = 0.f;
#pragma unroll
    for (int j = 0; j < 4; ++j) {
      E1[i][j] = __expf(z[i][j] - mx); s1 += E1[i][j];
      E2[i][j] = __expf(mn - z[i][j]); s2 += E2[i][j];
    }
#pragma unroll
    for (int o = 1; o < 16; o <<= 1) { s1 += __shfl_xor(s1, o); s2 += __shfl_xor(s2, o); }
    float r1 = 1.f / s1, r2 = 1.f / s2;
#pragma unroll
    for (int j = 0; j < 4; ++j) {
      E1[i][j] = fmaxf(E1[i][j] * r1, EPSF);
      E2[i][j] = fmaxf(E2[i][j] * r2, EPSF);
    }
  }

  if (!isk) {
    u16* ob = fqb + (((size_t)(h * NBLK + lt)) << 13);
#pragma unroll
    for (int i = 0; i < 4; ++i) {
      int row = ty * 4 + i;
      ushort4 ua, ub;
      ua.x = f2b(E1[i][0]); ua.y = f2b(E1[i][1]); ua.z = f2b(E1[i][2]); ua.w = f2b(E1[i][3]);
      ub.x = f2b(E2[i][0]); ub.y = f2b(E2[i][1]); ub.z = f2b(E2[i][2]); ub.w = f2b(E2[i][3]);
      *(ushort4*)(ob + row * 128 + tx * 4)      = ua;
      *(ushort4*)(ob + row * 128 + 64 + tx * 4) = ub;
    }
  } else {
#pragma unroll
    for (int i = 0; i < 4; ++i) {
      float* ob = fk + ((size_t)h * T_SEQ + lt * 64 + ty * 4 + i) * 128;
      *(float4*)(ob + tx * 4)      = make_float4(E1[i][0], E1[i][1], E1[i][2], E1[i][3]);
      *(float4*)(ob + 64 + tx * 4) = make_float4(E2[i][0], E2[i][1], E2[i][2], E2[i][3]);
    }
  }
}

// ---------------- K1b: V transpose to bf16 VT[d][key] ----------------
__global__ __launch_bounds__(256) void k_vt(const float* __restrict__ vg, u16* __restrict__ VT)
{
  __shared__ float sV[64 * 129];
  const int b = blockIdx.x, kvh = blockIdx.y, tid = threadIdx.x;
  for (int idx = tid * 4; idx < 8192; idx += 1024) {
    int r = idx >> 7, c = idx & 127;
    *(float4*)(sV + r * 129 + c) = *(const float4*)(vg + (size_t)(b * 64 + r) * (NKV * HS) + kvh * HS + c);
  }
  __syncthreads();
  const int lane = tid & 63, w = tid >> 6;
#pragma unroll
  for (int i = 0; i < 32; ++i) {
    int d = w * 32 + i;
    VT[((size_t)(kvh * 128 + d)) * T_SEQ + b * 64 + lane] = f2b(sV[lane * 129 + d]);
  }
}

// ---------------- K2: per-block partial states (transposed, bf16, +z) ----------------
__global__ __launch_bounds__(256) void k_state(
    const float* __restrict__ fk, const float* __restrict__ vg, u16* __restrict__ ST)
{
  __shared__ float sA[64 * 128];  // fk [j][f]
  __shared__ float sB[64 * 128];  // v  [j][d]
  const int b = blockIdx.x, h = blockIdx.y, tid = threadIdx.x;

  for (int idx = tid * 4; idx < 64 * 128; idx += 1024)
    *(float4*)(sA + idx) = *(const float4*)(fk + ((size_t)h * T_SEQ + b * 64) * 128 + idx);
  for (int idx = tid * 4; idx < 64 * 128; idx += 1024) {
    int r = idx >> 7, c = idx & 127;
    *(float4*)(sB + idx) = *(const float4*)(vg + (size_t)(b * 64 + r) * (NKV * HS) + (h >> 2) * HS + c);
  }
  __syncthreads();

  const int ty = tid >> 4, tx = tid & 15;   // f rows ty*8.., d cols tx*8..
  float acc[8][8];
#pragma unroll
  for (int i = 0; i < 8; ++i)
#pragma unroll
    for (int j = 0; j < 8; ++j) acc[i][j] = 0.f;

  for (int j = 0; j < 64; ++j) {
    float4 a0 = *(const float4*)(sA + j * 128 + ty * 8);
    float4 a1 = *(const float4*)(sA + j * 128 + ty * 8 + 4);
    float4 b0 = *(const float4*)(sB + j * 128 + tx * 8);
    float4 b1 = *(const float4*)(sB + j * 128 + tx * 8 + 4);
    float av[8] = {a0.x, a0.y, a0.z, a0.w, a1.x, a1.y, a1.z, a1.w};
    float bv[8] = {b0.x, b0.y, b0.z, b0.w, b1.x, b1.y, b1.z, b1.w};
#pragma unroll
    for (int i = 0; i < 8; ++i)
#pragma unroll
      for (int c = 0; c < 8; ++c) acc[i][c] += av[i] * bv[c];
  }

  u16* Sb = ST + ((size_t)(h * NBLK + b)) * 18432;
#pragma unroll
  for (int c = 0; c < 8; ++c) {
    int d = tx * 8 + c;
    ushort4 ua, ub;
    ua.x = f2b(acc[0][c]); ua.y = f2b(acc[1][c]); ua.z = f2b(acc[2][c]); ua.w = f2b(acc[3][c]);
    ub.x = f2b(acc[4][c]); ub.y = f2b(acc[5][c]); ub.z = f2b(acc[6][c]); ub.w = f2b(acc[7][c]);
    *(ushort4*)(Sb + d * 128 + ty * 8)     = ua;
    *(ushort4*)(Sb + d * 128 + ty * 8 + 4) = ub;
  }
  if (tid < 128) {
    float s = 0.f;
    for (int j = 0; j < 64; ++j) s += sA[j * 128 + tid];
    Sb[128 * 128 + tid] = f2b(s);
  }
  for (int idx = tid; idx < 15 * 128; idx += 256) Sb[129 * 128 + idx] = 0;
}

// ---------------- K3: inclusive prefix over blocks (in-place bf16, f32 acc) ----------------
__global__ __launch_bounds__(256) void k_prefix(u16* __restrict__ ST)
{
  const int h = blockIdx.y;
  const int e = blockIdx.x * 256 + threadIdx.x;   // < 18432
  u16* p = ST + (size_t)h * NBLK * 18432 + e;
  float acc = 0.f;
#pragma unroll 4
  for (int b = 0; b < NBLK; ++b) {
    acc += b2f(p[(size_t)b * 18432]);
    p[(size_t)b * 18432] = f2b(acc);
  }
}

// ---------------- K4: main attention (MFMA) ----------------
// grid (NBLK, NH), 256 threads = 4 waves; wave w owns q-rows [w*16, w*16+16)
__global__ __launch_bounds__(256, 3) void k_main(
    const float* __restrict__ qg, const float* __restrict__ kg,
    const u16* __restrict__ fqb, const u16* __restrict__ ST, const u16* __restrict__ VT,
    const float* __restrict__ wfac, float* __restrict__ out)
{
  __shared__ u16 RA[64 * LDP];    // A-operand: FQ -> Q -> P (K-major rows)
  __shared__ u16 RB[128 * LDP];   // B-operand: S^T halves -> K -> V^T
  const int B = blockIdx.x, h = blockIdx.y, tid = threadIdx.x;
  const int lane = tid & 63, w = tid >> 6;
  const int quad = lane >> 4, txn = lane & 15;
  const int arow = w * 16 + txn;     // A row this lane reads
  const int koff = quad * 8;

  const f32x4 vzero = {0.f, 0.f, 0.f, 0.f};
  f32x4 y[8];
#pragma unroll
  for (int t = 0; t < 8; ++t) y[t] = vzero;
  float sln[4] = {0.f, 0.f, 0.f, 0.f};

  // ---- linear part: Y += FQ · S_cum[B-2]  (+ z column -> sln) ----
  if (B >= 2) {
    const u16* fsrc = fqb + ((size_t)(h * NBLK + B)) * 8192;
    for (int idx = tid * 4; idx < 8192; idx += 1024) {
      int r = idx >> 7, c = idx & 127;
      *(ushort4*)(RA + r * LDP + c) = *(const ushort4*)(fsrc + idx);
    }
    const u16* ssrc = ST + ((size_t)(h * NBLK + (B - 2))) * 18432;
    for (int idx = tid * 4; idx < 8192; idx += 1024) {      // S^T rows 0..63 (d)
      int r = idx >> 7, c = idx & 127;
      *(ushort4*)(RB + r * LDP + c) = *(const ushort4*)(ssrc + idx);
    }
    __syncthreads();
    f32x4 a8 = vzero;
#pragma unroll
    for (int ks = 0; ks < 4; ++ks) {
      bf16x8 a = *(const bf16x8*)(RA + arow * LDP + ks * 32 + koff);
#pragma unroll
      for (int t = 0; t < 4; ++t) {
        bf16x8 bb = *(const bf16x8*)(RB + (t * 16 + txn) * LDP + ks * 32 + koff);
        y[t] = __builtin_amdgcn_mfma_f32_16x16x32_bf16(a, bb, y[t], 0, 0, 0);
      }
    }
    __syncthreads();
    for (int idx = tid * 4; idx < 10240; idx += 1024) {     // S^T rows 64..143
      int r = idx >> 7, c = idx & 127;
      *(ushort4*)(RB + r * LDP + c) = *(const ushort4*)(ssrc + 8192 + idx);
    }
    __syncthreads();
#pragma unroll
    for (int ks = 0; ks < 4; ++ks) {
      bf16x8 a = *(const bf16x8*)(RA + arow * LDP + ks * 32 + koff);
#pragma unroll
      for (int t = 4; t < 8; ++t) {
        bf16x8 bb = *(const bf16x8*)(RB + (t * 16 + txn - 64) * LDP + ks * 32 + koff);
        y[t] = __builtin_amdgcn_mfma_f32_16x16x32_bf16(a, bb, y[t], 0, 0, 0);
      }
      bf16x8 b8 = *(const bf16x8*)(RB + (64 + txn) * LDP + ks * 32 + koff);
      a8 = __builtin_amdgcn_mfma_f32_16x16x32_bf16(a, b8, a8, 0, 0, 0);
    }
#pragma unroll
    for (int r = 0; r < 4; ++r) sln[r] = __shfl(a8[r], lane & 48);  // col 128 lives on txn==0
    __syncthreads();
  }

  // ---- stage Q (f32->bf16) into RA, K (two 64-blocks) into RB ----
  const int kb0 = (B >= 1) ? B - 1 : 0;
  {
    const float* qs = qg + (size_t)(B * 64) * (NH * HS) + h * HS;
    for (int idx = tid * 4; idx < 8192; idx += 1024) {
      int r = idx >> 7, c = idx & 127;
      float4 v4 = *(const float4*)(qs + (size_t)r * (NH * HS) + c);
      ushort4 u; u.x = f2b(v4.x); u.y = f2b(v4.y); u.z = f2b(v4.z); u.w = f2b(v4.w);
      *(ushort4*)(RA + r * LDP + c) = u;
    }
    for (int idx = tid * 4; idx < 16384; idx += 1024) {
      int r = idx >> 7, c = idx & 127;
      int key = (r < 64) ? (kb0 * 64 + r) : (B * 64 + (r - 64));
      float4 v4 = *(const float4*)(kg + (size_t)key * (NKV * HS) + (h >> 2) * HS + c);
      ushort4 u; u.x = f2b(v4.x); u.y = f2b(v4.y); u.z = f2b(v4.z); u.w = f2b(v4.w);
      *(ushort4*)(RB + r * LDP + c) = u;
    }
  }
  __syncthreads();

  // ---- scores ----
  f32x4 s[8];
#pragma unroll
  for (int t = 0; t < 8; ++t) s[t] = vzero;
#pragma unroll
  for (int ks = 0; ks < 4; ++ks) {
    bf16x8 a = *(const bf16x8*)(RA + arow * LDP + ks * 32 + koff);
#pragma unroll
    for (int t = 0; t < 8; ++t) {
      bf16x8 bb = *(const bf16x8*)(RB + (t * 16 + txn) * LDP + ks * 32 + koff);
      s[t] = __builtin_amdgcn_mfma_f32_16x16x32_bf16(a, bb, s[t], 0, 0, 0);
    }
  }

  // ---- masked softmax, write P (bf16) into RA rows (wave-private) ----
  float wf = wfac[h];
  wf = 1.f / (1.f + __expf(-wf));
  const float scale = 0.08838834764831845f;
  float ssum[4];
#pragma unroll
  for (int r = 0; r < 4; ++r) {
    const int irow = w * 16 + quad * 4 + r;
    float sv[8];
    float m = -1e30f;
#pragma unroll
    for (int t = 0; t < 8; ++t) {
      float x = s[t][r] * scale;
      bool msk = (t < 4) ? (B == 0) : ((t - 4) * 16 + txn > irow);
      x = msk ? -1e30f : x;
      sv[t] = x;
      m = fmaxf(m, x);
    }
#pragma unroll
    for (int o = 1; o < 16; o <<= 1) m = fmaxf(m, __shfl_xor(m, o));
    float ss = 0.f;
#pragma unroll
    for (int t = 0; t < 8; ++t) {
      float e = (sv[t] > -1e29f) ? wf * __expf(sv[t] - m) : 0.f;
      ss += e;
      RA[irow * LDP + t * 16 + txn] = f2b(e);
    }
#pragma unroll
    for (int o = 1; o < 16; o <<= 1) ss += __shfl_xor(ss, o);
    ssum[r] = ss;
  }
  __syncthreads();   // all waves done reading K before V^T overwrites RB

  // ---- stage V^T (bf16 ws) into RB ----
  {
    const u16* vts = VT + (size_t)((h >> 2) * 128) * T_SEQ;
    for (int idx = tid * 4; idx < 16384; idx += 1024) {
      int r = idx >> 7, c = idx & 127;        // r = d, c = key slot
      int key = (c < 64) ? (kb0 * 64 + c) : (B * 64 + (c - 64));
      *(ushort4*)(RB + r * LDP + c) = *(const ushort4*)(vts + (size_t)r * T_SEQ + key);
    }
  }
  __syncthreads();

  // ---- PV ----
#pragma unroll
  for (int ks = 0; ks < 4; ++ks) {
    if (B == 0 && ks < 2) continue;   // P == 0 on those keys
    bf16x8 a = *(const bf16x8*)(RA + arow * LDP + ks * 32 + koff);
#pragma unroll
    for (int t = 0; t < 8; ++t) {
      bf16x8 bb = *(const bf16x8*)(RB + (t * 16 + txn) * LDP + ks * 32 + koff);
      y[t] = __builtin_amdgcn_mfma_f32_16x16x32_bf16(a, bb, y[t], 0, 0, 0);
    }
  }

  // ---- epilogue ----
  const size_t obase = ((size_t)h * T_SEQ + B * 64) * HS;
#pragma unroll
  for (int r = 0; r < 4; ++r) {
    float inv = 1.f / (ssum[r] + sln[r]);
    int irow = w * 16 + quad * 4 + r;
#pragma unroll
    for (int t = 0; t < 8; ++t)
      out[obase + (size_t)irow * HS + t * 16 + txn] = y[t][r] * inv;
  }
}

extern "C" void kernel_launch(void* const* d_in, const int* in_sizes, int n_in,
                              void* d_out, int out_size, void* d_ws, size_t ws_size,
                              hipStream_t stream) {
  const float* q    = (const float*)d_in[0];
  const float* k    = (const float*)d_in[1];
  const float* v    = (const float*)d_in[2];
  const float* wq   = (const float*)d_in[3];
  const float* wk   = (const float*)d_in[4];
  const float* wfac = (const float*)d_in[5];
  float* out = (float*)d_out;
  char* wsb = (char*)d_ws;

  u16*   fqb = (u16*)(wsb + FQB_OFF);
  float* fk  = (float*)(wsb + FK_OFF);
  u16*   ST  = (u16*)(wsb + ST_OFF);
  u16*   VT  = (u16*)(wsb + VT_OFF);

  k_fmap  <<<dim3(NBLK, NH, 2), 256, 0, stream>>>(q, k, wq, wk, fqb, fk);
  k_vt    <<<dim3(NBLK, NKV),   256, 0, stream>>>(v, VT);
  k_state <<<dim3(NBLK, NH),    256, 0, stream>>>(fk, v, ST);
  k_prefix<<<dim3(72, NH),      256, 0, stream>>>(ST);
  k_main  <<<dim3(NBLK, NH),    256, 0, stream>>>(q, k, fqb, ST, VT, wfac, out);
}

// Round 3
// 197.806 us; speedup vs baseline: 1.5985x; 1.1771x over previous
//
#include <hip/hip_runtime.h>
#include <math.h>

#define T_SEQ 2048
#define NH    32
#define NKV   8
#define HS    128
#define FD    64
#define NBLK  32          // T_SEQ / 64
#define EPSF  1e-12f
#define LDP   136         // k_main LDS row pitch (bf16 elems)

typedef unsigned short u16;
typedef __bf16 bf16x8 __attribute__((ext_vector_type(8)));
typedef float  f32x4  __attribute__((ext_vector_type(4)));

__device__ __forceinline__ u16 f2b(float f) {
  unsigned u = __builtin_bit_cast(unsigned, f);
  return (u16)((u + 0x7fffu + ((u >> 16) & 1u)) >> 16);
}

// ws layout (bytes):
//  fqb: bf16 [NH][NBLK][64 q][128 f]      16,777,216
//  FKT: bf16 [NH][128 f][T j]             16,777,216
//  ST : bf16 [NH][NBLK][144 d][128 f]     37,748,736  (row128=z; 129..143 unused)
//  VT : bf16 [NKV][128 d][T key]           4,194,304
//  WT : bf16 [2][NH][64 f][128 d]          1,048,576
#define FQB_OFF 0
#define FKT_OFF 16777216
#define ST_OFF  33554432
#define VT_OFF  71303168
#define WT_OFF  75497472

// ---------------- K0: weight transpose to bf16 WT[f][d] ----------------
__global__ __launch_bounds__(256) void k_wt(
    const float* __restrict__ wq, const float* __restrict__ wk, u16* __restrict__ WT)
{
  __shared__ float sW[128 * 68];
  const int h = blockIdx.x, isk = blockIdx.y, tid = threadIdx.x;
  const float* src = (isk ? wk : wq) + (size_t)h * HS * FD;
  for (int idx = tid * 4; idx < 8192; idx += 1024) {
    int r = idx >> 6, c = idx & 63;
    *(float4*)(sW + r * 68 + c) = *(const float4*)(src + idx);
  }
  __syncthreads();
  u16* dst = WT + ((size_t)(isk * NH + h)) * 8192;
  for (int i = 0; i < 8; ++i) {
    int ch = tid + i * 256;              // 2048 chunks of 4
    int f = ch >> 5, d4 = (ch & 31) * 4;
    ushort4 u;
    u.x = f2b(sW[(d4 + 0) * 68 + f]);
    u.y = f2b(sW[(d4 + 1) * 68 + f]);
    u.z = f2b(sW[(d4 + 2) * 68 + f]);
    u.w = f2b(sW[(d4 + 3) * 68 + f]);
    *(ushort4*)(dst + f * 128 + d4) = u;
  }
}

// ---------------- K1: feature maps (MFMA) ----------------
// grid (NBLK, NH, 2), 256 thr = 4 waves; wave w owns q-rows [w*16, w*16+16)
__global__ __launch_bounds__(256) void k_fmap(
    const float* __restrict__ qg, const float* __restrict__ kg,
    const u16* __restrict__ WT,
    u16* __restrict__ fqb, u16* __restrict__ FKT)
{
  __shared__ __align__(16) u16 smem[2 * 64 * 136];
  u16* sX = smem;              // X tile [q][d] pitch 136 ; later aliased as output buf
  u16* sW = smem + 64 * 136;   // WT rows [f][d] pitch 136
  const int lt = blockIdx.x, h = blockIdx.y, isk = blockIdx.z;
  const int tid = threadIdx.x, lane = tid & 63, w = tid >> 6;
  const int quad = lane >> 4, txn = lane & 15;

  // stage X (f32 -> bf16)
  const float* xbase = isk ? (kg + (h >> 2) * HS) : (qg + h * HS);
  const int    xstr  = isk ? (NKV * HS) : (NH * HS);
  for (int idx = tid * 4; idx < 8192; idx += 1024) {
    int r = idx >> 7, c = idx & 127;
    float4 v4 = *(const float4*)(xbase + (size_t)(lt * 64 + r) * xstr + c);
    ushort4 u; u.x = f2b(v4.x); u.y = f2b(v4.y); u.z = f2b(v4.z); u.w = f2b(v4.w);
    *(ushort4*)(sX + r * 136 + c) = u;
  }
  // stage WT rows (bf16, direct)
  const u16* wt = WT + ((size_t)(isk * NH + h)) * 8192;
  for (int i = 0; i < 4; ++i) {
    int ch = tid + i * 256;              // 1024 chunks of 8
    int row = ch >> 4, d8 = (ch & 15) * 8;
    *(uint4*)(sW + row * 136 + d8) = *(const uint4*)(wt + row * 128 + d8);
  }
  __syncthreads();

  // z = X·W^T : C[q][f], m-tile = wave, 4 n-tiles, K=128
  const int arow = w * 16 + txn;
  const f32x4 vzero = {0.f, 0.f, 0.f, 0.f};
  f32x4 zt[4] = {vzero, vzero, vzero, vzero};
#pragma unroll
  for (int ks = 0; ks < 4; ++ks) {
    bf16x8 a = *(const bf16x8*)(sX + arow * 136 + ks * 32 + quad * 8);
#pragma unroll
    for (int nt = 0; nt < 4; ++nt) {
      bf16x8 bb = *(const bf16x8*)(sW + (nt * 16 + txn) * 136 + ks * 32 + quad * 8);
      zt[nt] = __builtin_amdgcn_mfma_f32_16x16x32_bf16(a, bb, zt[nt], 0, 0, 0);
    }
  }

  // dual softmax over 64 features per q-row (row = quad*4+r in wave's m-tile)
  float E1[4][4], E2[4][4];   // [r][nt]
#pragma unroll
  for (int r = 0; r < 4; ++r) {
    float zv[4];
    float mx = -1e30f, mn = 1e30f;
#pragma unroll
    for (int nt = 0; nt < 4; ++nt) {
      zv[nt] = zt[nt][r];
      mx = fmaxf(mx, zv[nt]); mn = fminf(mn, zv[nt]);
    }
#pragma unroll
    for (int o = 1; o < 16; o <<= 1) {
      mx = fmaxf(mx, __shfl_xor(mx, o));
      mn = fminf(mn, __shfl_xor(mn, o));
    }
    float e1[4], e2[4], s1 = 0.f, s2 = 0.f;
#pragma unroll
    for (int nt = 0; nt < 4; ++nt) {
      e1[nt] = __expf(zv[nt] - mx); s1 += e1[nt];
      e2[nt] = __expf(mn - zv[nt]); s2 += e2[nt];
    }
#pragma unroll
    for (int o = 1; o < 16; o <<= 1) { s1 += __shfl_xor(s1, o); s2 += __shfl_xor(s2, o); }
    float r1 = 1.f / s1, r2 = 1.f / s2;
#pragma unroll
    for (int nt = 0; nt < 4; ++nt) {
      E1[r][nt] = fmaxf(e1[nt] * r1, EPSF);
      E2[r][nt] = fmaxf(e2[nt] * r2, EPSF);
    }
  }

  __syncthreads();   // all mfma LDS reads done; safe to alias sX as output

  if (!isk) {
    // fqb row-major [q][128 f] via LDS pitch 136
#pragma unroll
    for (int r = 0; r < 4; ++r) {
      int row = w * 16 + quad * 4 + r;
#pragma unroll
      for (int nt = 0; nt < 4; ++nt) {
        sX[row * 136 + nt * 16 + txn]      = f2b(E1[r][nt]);
        sX[row * 136 + 64 + nt * 16 + txn] = f2b(E2[r][nt]);
      }
    }
    __syncthreads();
    u16* ob = fqb + ((size_t)(h * NBLK + lt)) * 8192;
    for (int i = 0; i < 4; ++i) {
      int ch = tid + i * 256;
      int row = ch >> 4, f8 = (ch & 15) * 8;
      *(uint4*)(ob + row * 128 + f8) = *(const uint4*)(sX + row * 136 + f8);
    }
  } else {
    // FKT transposed [f][j] via LDS pitch 68
#pragma unroll
    for (int r = 0; r < 4; ++r) {
      int j = w * 16 + quad * 4 + r;
#pragma unroll
      for (int nt = 0; nt < 4; ++nt) {
        sX[(nt * 16 + txn) * 68 + j]        = f2b(E1[r][nt]);
        sX[(nt * 16 + txn + 64) * 68 + j]   = f2b(E2[r][nt]);
      }
    }
    __syncthreads();
    u16* ob = FKT + (size_t)h * 128 * T_SEQ + lt * 64;
    for (int i = 0; i < 8; ++i) {
      int ch = tid + i * 256;              // 2048 chunks of 4
      int row = ch >> 4, j4 = (ch & 15) * 4;
      *(ushort4*)(ob + (size_t)row * T_SEQ + j4) = *(const ushort4*)(sX + row * 68 + j4);
    }
  }
}

// ---------------- K1b: V transpose to bf16 VT[d][key] ----------------
__global__ __launch_bounds__(256) void k_vt(const float* __restrict__ vg, u16* __restrict__ VT)
{
  __shared__ float sV[64 * 129];
  const int b = blockIdx.x, kvh = blockIdx.y, tid = threadIdx.x;
  for (int idx = tid * 4; idx < 8192; idx += 1024) {
    int r = idx >> 7, c = idx & 127;
    *(float4*)(sV + r * 129 + c) = *(const float4*)(vg + (size_t)(b * 64 + r) * (NKV * HS) + kvh * HS + c);
  }
  __syncthreads();
  const int lane = tid & 63, w = tid >> 6;
#pragma unroll
  for (int i = 0; i < 32; ++i) {
    int d = w * 32 + i;
    VT[((size_t)(kvh * 128 + d)) * T_SEQ + b * 64 + lane] = f2b(sV[lane * 129 + d]);
  }
}

// ---------------- K2: fused state + prefix scan (MFMA) ----------------
// grid (8 dchunk, 2 fhalf, NH), 256 thr = 4 waves; wave w owns n-tile w (16 f)
__global__ __launch_bounds__(256) void k_scan(
    const u16* __restrict__ FKT, const u16* __restrict__ VT, u16* __restrict__ ST)
{
  __shared__ __align__(16) u16 sVT[16 * 72];
  __shared__ __align__(16) u16 sFK[64 * 72];
  __shared__ __align__(16) u16 sOne[16 * 72];
  __shared__ __align__(16) u16 sO[16 * 72];
  const int dc = blockIdx.x, fh = blockIdx.y, h = blockIdx.z;
  const int tid = threadIdx.x, lane = tid & 63, w = tid >> 6;
  const int quad = lane >> 4, txn = lane & 15;
  const bool doz = (dc == 0);

  // ones tile for z-row MFMA
  for (int idx = tid * 8; idx < 16 * 72; idx += 2048) {
    ushort4 o4; o4.x = 0x3F80; o4.y = 0x3F80; o4.z = 0x3F80; o4.w = 0x3F80;
    *(ushort4*)(sOne + idx) = o4;
    *(ushort4*)(sOne + idx + 4) = o4;
  }

  const u16* vbase = VT + ((size_t)((h >> 2) * 128 + dc * 16)) * T_SEQ;
  const u16* fbase = FKT + ((size_t)(h * 128 + fh * 64)) * T_SEQ;

  // prefetch b=0
  const int srow = tid >> 4, sj4 = (tid & 15) * 4;
  ushort4 rv, rf[4];
  rv = *(const ushort4*)(vbase + (size_t)srow * T_SEQ + sj4);
#pragma unroll
  for (int i = 0; i < 4; ++i) {
    int ch = tid + i * 256;
    int fr = ch >> 4, fj4 = (ch & 15) * 4;
    rf[i] = *(const ushort4*)(fbase + (size_t)fr * T_SEQ + fj4);
  }

  const f32x4 vzero = {0.f, 0.f, 0.f, 0.f};
  f32x4 acc = vzero, zacc = vzero;

  for (int b = 0; b < NBLK; ++b) {
    __syncthreads();            // prev mfma reads + sO readout done
    *(ushort4*)(sVT + srow * 72 + sj4) = rv;
#pragma unroll
    for (int i = 0; i < 4; ++i) {
      int ch = tid + i * 256;
      int fr = ch >> 4, fj4 = (ch & 15) * 4;
      *(ushort4*)(sFK + fr * 72 + fj4) = rf[i];
    }
    __syncthreads();
    if (b + 1 < NBLK) {         // prefetch next chunk; latency hidden by mfma+writes
      rv = *(const ushort4*)(vbase + (size_t)srow * T_SEQ + (b + 1) * 64 + sj4);
#pragma unroll
      for (int i = 0; i < 4; ++i) {
        int ch = tid + i * 256;
        int fr = ch >> 4, fj4 = (ch & 15) * 4;
        rf[i] = *(const ushort4*)(fbase + (size_t)fr * T_SEQ + (b + 1) * 64 + fj4);
      }
    }
#pragma unroll
    for (int ks = 0; ks < 2; ++ks) {
      bf16x8 a  = *(const bf16x8*)(sVT + txn * 72 + ks * 32 + quad * 8);
      bf16x8 bb = *(const bf16x8*)(sFK + (w * 16 + txn) * 72 + ks * 32 + quad * 8);
      acc = __builtin_amdgcn_mfma_f32_16x16x32_bf16(a, bb, acc, 0, 0, 0);
      if (doz) {
        bf16x8 ao = *(const bf16x8*)(sOne + txn * 72 + ks * 32 + quad * 8);
        zacc = __builtin_amdgcn_mfma_f32_16x16x32_bf16(ao, bb, zacc, 0, 0, 0);
      }
    }
    // cumulative state (bf16) -> sO -> global
#pragma unroll
    for (int r = 0; r < 4; ++r)
      sO[(quad * 4 + r) * 72 + w * 16 + txn] = f2b(acc[r]);
    if (doz && quad == 0)
      ST[(((size_t)(h * NBLK + b)) * 144 + 128) * 128 + fh * 64 + w * 16 + txn] = f2b(zacc[0]);
    __syncthreads();
    *(ushort4*)(ST + (((size_t)(h * NBLK + b)) * 144 + dc * 16 + srow) * 128 + fh * 64 + sj4)
        = *(const ushort4*)(sO + srow * 72 + sj4);
  }
}

// ---------------- K4: main attention (MFMA) ----------------
// grid (NBLK, NH), 256 threads = 4 waves; wave w owns q-rows [w*16, w*16+16)
__global__ __launch_bounds__(256, 3) void k_main(
    const float* __restrict__ qg, const float* __restrict__ kg,
    const u16* __restrict__ fqb, const u16* __restrict__ ST, const u16* __restrict__ VT,
    const float* __restrict__ wfac, float* __restrict__ out)
{
  __shared__ u16 RA[64 * LDP];    // A-operand: FQ -> Q -> P (K-major rows)
  __shared__ u16 RB[128 * LDP];   // B-operand: S^T halves -> K -> V^T
  const int B = blockIdx.x, h = blockIdx.y, tid = threadIdx.x;
  const int lane = tid & 63, w = tid >> 6;
  const int quad = lane >> 4, txn = lane & 15;
  const int arow = w * 16 + txn;
  const int koff = quad * 8;

  const f32x4 vzero = {0.f, 0.f, 0.f, 0.f};
  f32x4 y[8];
#pragma unroll
  for (int t = 0; t < 8; ++t) y[t] = vzero;
  float sln[4] = {0.f, 0.f, 0.f, 0.f};

  // ---- linear part: Y += FQ · S_cum[B-2]  (+ z column -> sln) ----
  if (B >= 2) {
    const u16* fsrc = fqb + ((size_t)(h * NBLK + B)) * 8192;
    for (int idx = tid * 4; idx < 8192; idx += 1024) {
      int r = idx >> 7, c = idx & 127;
      *(ushort4*)(RA + r * LDP + c) = *(const ushort4*)(fsrc + idx);
    }
    const u16* ssrc = ST + ((size_t)(h * NBLK + (B - 2))) * 18432;
    for (int idx = tid * 4; idx < 8192; idx += 1024) {      // S^T rows 0..63 (d)
      int r = idx >> 7, c = idx & 127;
      *(ushort4*)(RB + r * LDP + c) = *(const ushort4*)(ssrc + idx);
    }
    __syncthreads();
    f32x4 a8 = vzero;
#pragma unroll
    for (int ks = 0; ks < 4; ++ks) {
      bf16x8 a = *(const bf16x8*)(RA + arow * LDP + ks * 32 + koff);
#pragma unroll
      for (int t = 0; t < 4; ++t) {
        bf16x8 bb = *(const bf16x8*)(RB + (t * 16 + txn) * LDP + ks * 32 + koff);
        y[t] = __builtin_amdgcn_mfma_f32_16x16x32_bf16(a, bb, y[t], 0, 0, 0);
      }
    }
    __syncthreads();
    for (int idx = tid * 4; idx < 10240; idx += 1024) {     // S^T rows 64..143
      int r = idx >> 7, c = idx & 127;
      *(ushort4*)(RB + r * LDP + c) = *(const ushort4*)(ssrc + 8192 + idx);
    }
    __syncthreads();
#pragma unroll
    for (int ks = 0; ks < 4; ++ks) {
      bf16x8 a = *(const bf16x8*)(RA + arow * LDP + ks * 32 + koff);
#pragma unroll
      for (int t = 4; t < 8; ++t) {
        bf16x8 bb = *(const bf16x8*)(RB + (t * 16 + txn - 64) * LDP + ks * 32 + koff);
        y[t] = __builtin_amdgcn_mfma_f32_16x16x32_bf16(a, bb, y[t], 0, 0, 0);
      }
      bf16x8 b8 = *(const bf16x8*)(RB + (64 + txn) * LDP + ks * 32 + koff);
      a8 = __builtin_amdgcn_mfma_f32_16x16x32_bf16(a, b8, a8, 0, 0, 0);
    }
#pragma unroll
    for (int r = 0; r < 4; ++r) sln[r] = __shfl(a8[r], lane & 48);  // col 0 = z
    __syncthreads();
  }

  // ---- stage Q (f32->bf16) into RA, K (two 64-blocks) into RB ----
  const int kb0 = (B >= 1) ? B - 1 : 0;
  {
    const float* qs = qg + (size_t)(B * 64) * (NH * HS) + h * HS;
    for (int idx = tid * 4; idx < 8192; idx += 1024) {
      int r = idx >> 7, c = idx & 127;
      float4 v4 = *(const float4*)(qs + (size_t)r * (NH * HS) + c);
      ushort4 u; u.x = f2b(v4.x); u.y = f2b(v4.y); u.z = f2b(v4.z); u.w = f2b(v4.w);
      *(ushort4*)(RA + r * LDP + c) = u;
    }
    for (int idx = tid * 4; idx < 16384; idx += 1024) {
      int r = idx >> 7, c = idx & 127;
      int key = (r < 64) ? (kb0 * 64 + r) : (B * 64 + (r - 64));
      float4 v4 = *(const float4*)(kg + (size_t)key * (NKV * HS) + (h >> 2) * HS + c);
      ushort4 u; u.x = f2b(v4.x); u.y = f2b(v4.y); u.z = f2b(v4.z); u.w = f2b(v4.w);
      *(ushort4*)(RB + r * LDP + c) = u;
    }
  }
  __syncthreads();

  // ---- scores ----
  f32x4 s[8];
#pragma unroll
  for (int t = 0; t < 8; ++t) s[t] = vzero;
#pragma unroll
  for (int ks = 0; ks < 4; ++ks) {
    bf16x8 a = *(const bf16x8*)(RA + arow * LDP + ks * 32 + koff);
#pragma unroll
    for (int t = 0; t < 8; ++t) {
      bf16x8 bb = *(const bf16x8*)(RB + (t * 16 + txn) * LDP + ks * 32 + koff);
      s[t] = __builtin_amdgcn_mfma_f32_16x16x32_bf16(a, bb, s[t], 0, 0, 0);
    }
  }

  // ---- masked softmax, write P (bf16) into RA rows (wave-private) ----
  float wf = wfac[h];
  wf = 1.f / (1.f + __expf(-wf));
  const float scale = 0.08838834764831845f;
  float ssum[4];
#pragma unroll
  for (int r = 0; r < 4; ++r) {
    const int irow = w * 16 + quad * 4 + r;
    float sv[8];
    float m = -1e30f;
#pragma unroll
    for (int t = 0; t < 8; ++t) {
      float x = s[t][r] * scale;
      bool msk = (t < 4) ? (B == 0) : ((t - 4) * 16 + txn > irow);
      x = msk ? -1e30f : x;
      sv[t] = x;
      m = fmaxf(m, x);
    }
#pragma unroll
    for (int o = 1; o < 16; o <<= 1) m = fmaxf(m, __shfl_xor(m, o));
    float ss = 0.f;
#pragma unroll
    for (int t = 0; t < 8; ++t) {
      float e = (sv[t] > -1e29f) ? wf * __expf(sv[t] - m) : 0.f;
      ss += e;
      RA[irow * LDP + t * 16 + txn] = f2b(e);
    }
#pragma unroll
    for (int o = 1; o < 16; o <<= 1) ss += __shfl_xor(ss, o);
    ssum[r] = ss;
  }
  __syncthreads();   // all waves done reading K before V^T overwrites RB

  // ---- stage V^T (bf16 ws) into RB ----
  {
    const u16* vts = VT + (size_t)((h >> 2) * 128) * T_SEQ;
    for (int idx = tid * 4; idx < 16384; idx += 1024) {
      int r = idx >> 7, c = idx & 127;        // r = d, c = key slot
      int key = (c < 64) ? (kb0 * 64 + c) : (B * 64 + (c - 64));
      *(ushort4*)(RB + r * LDP + c) = *(const ushort4*)(vts + (size_t)r * T_SEQ + key);
    }
  }
  __syncthreads();

  // ---- PV ----
#pragma unroll
  for (int ks = 0; ks < 4; ++ks) {
    if (B == 0 && ks < 2) continue;   // P == 0 on those keys
    bf16x8 a = *(const bf16x8*)(RA + arow * LDP + ks * 32 + koff);
#pragma unroll
    for (int t = 0; t < 8; ++t) {
      bf16x8 bb = *(const bf16x8*)(RB + (t * 16 + txn) * LDP + ks * 32 + koff);
      y[t] = __builtin_amdgcn_mfma_f32_16x16x32_bf16(a, bb, y[t], 0, 0, 0);
    }
  }

  // ---- epilogue ----
  const size_t obase = ((size_t)h * T_SEQ + B * 64) * HS;
#pragma unroll
  for (int r = 0; r < 4; ++r) {
    float inv = 1.f / (ssum[r] + sln[r]);
    int irow = w * 16 + quad * 4 + r;
#pragma unroll
    for (int t = 0; t < 8; ++t)
      out[obase + (size_t)irow * HS + t * 16 + txn] = y[t][r] * inv;
  }
}

extern "C" void kernel_launch(void* const* d_in, const int* in_sizes, int n_in,
                              void* d_out, int out_size, void* d_ws, size_t ws_size,
                              hipStream_t stream) {
  const float* q    = (const float*)d_in[0];
  const float* k    = (const float*)d_in[1];
  const float* v    = (const float*)d_in[2];
  const float* wq   = (const float*)d_in[3];
  const float* wk   = (const float*)d_in[4];
  const float* wfac = (const float*)d_in[5];
  float* out = (float*)d_out;
  char* wsb = (char*)d_ws;

  u16* fqb = (u16*)(wsb + FQB_OFF);
  u16* FKT = (u16*)(wsb + FKT_OFF);
  u16* ST  = (u16*)(wsb + ST_OFF);
  u16* VT  = (u16*)(wsb + VT_OFF);
  u16* WT  = (u16*)(wsb + WT_OFF);

  k_wt   <<<dim3(NH, 2),       256, 0, stream>>>(wq, wk, WT);
  k_vt   <<<dim3(NBLK, NKV),   256, 0, stream>>>(v, VT);
  k_fmap <<<dim3(NBLK, NH, 2), 256, 0, stream>>>(q, k, WT, fqb, FKT);
  k_scan <<<dim3(8, 2, NH),    256, 0, stream>>>(FKT, VT, ST);
  k_main <<<dim3(NBLK, NH),    256, 0, stream>>>(q, k, fqb, ST, VT, wfac, out);
}

// Round 4
// 176.927 us; speedup vs baseline: 1.7871x; 1.1180x over previous
//
#include <hip/hip_runtime.h>
#include <math.h>

#define T_SEQ 2048
#define NH    32
#define NKV   8
#define HS    128
#define FD    64
#define NBLK  32          // T_SEQ / 64
#define EPSF  1e-12f
#define LDP   136         // k_main/k_fmap LDS row pitch (bf16 elems)

typedef unsigned short u16;
typedef __bf16 bf16x8 __attribute__((ext_vector_type(8)));
typedef float  f32x4  __attribute__((ext_vector_type(4)));

__device__ __forceinline__ u16 f2b(float f) {
  unsigned u = __builtin_bit_cast(unsigned, f);
  return (u16)((u + 0x7fffu + ((u >> 16) & 1u)) >> 16);
}

// ws layout (bytes):
//  fqb: bf16 [NH][NBLK][64 q][128 f]      16,777,216
//  FKT: bf16 [NH][128 f][T j]             16,777,216
//  ST : bf16 [NH][NBLK][144 d][128 f]     37,748,736  (row128=z; 129..143 unused)
//  VT : bf16 [NKV][128 d][T key]           4,194,304
//  WT : bf16 [2][NH][64 f][128 d]          1,048,576
#define FQB_OFF 0
#define FKT_OFF 16777216
#define ST_OFF  33554432
#define VT_OFF  71303168
#define WT_OFF  75497472

// ---------------- K0: fused weight transpose + V transpose ----------------
// grid 320 blocks: [0,64) = WT transpose, [64,320) = VT transpose
__global__ __launch_bounds__(256) void k_pre(
    const float* __restrict__ wq, const float* __restrict__ wk,
    const float* __restrict__ vg,
    u16* __restrict__ WT, u16* __restrict__ VT)
{
  __shared__ float sB[128 * 68];
  const int bx = blockIdx.x, tid = threadIdx.x;

  if (bx < 64) {
    // ---- WT: [d][f] f32 -> [f][d] bf16 ----
    const int h = bx >> 1, isk = bx & 1;
    const float* src = (isk ? wk : wq) + (size_t)h * HS * FD;
    for (int idx = tid * 4; idx < 8192; idx += 1024) {
      int r = idx >> 6, c = idx & 63;
      *(float4*)(sB + r * 68 + c) = *(const float4*)(src + idx);
    }
    __syncthreads();
    u16* dst = WT + ((size_t)(isk * NH + h)) * 8192;
    for (int i = 0; i < 8; ++i) {
      int ch = tid + i * 256;              // 2048 chunks of 4
      int f = ch >> 5, d4 = (ch & 31) * 4;
      ushort4 u;
      u.x = f2b(sB[(d4 + 0) * 68 + f]);
      u.y = f2b(sB[(d4 + 1) * 68 + f]);
      u.z = f2b(sB[(d4 + 2) * 68 + f]);
      u.w = f2b(sB[(d4 + 3) * 68 + f]);
      *(ushort4*)(dst + f * 128 + d4) = u;
    }
  } else {
    // ---- VT: v [key][d] f32 -> [d][key] bf16 ----
    const int idx2 = bx - 64;
    const int b = idx2 & 31, kvh = idx2 >> 5;
    float* sV = sB;                        // 64*129 floats
    for (int idx = tid * 4; idx < 8192; idx += 1024) {
      int r = idx >> 7, c = idx & 127;
      *(float4*)(sV + r * 129 + c) = *(const float4*)(vg + (size_t)(b * 64 + r) * (NKV * HS) + kvh * HS + c);
    }
    __syncthreads();
    const int lane = tid & 63, w = tid >> 6;
#pragma unroll
    for (int i = 0; i < 32; ++i) {
      int d = w * 32 + i;
      VT[((size_t)(kvh * 128 + d)) * T_SEQ + b * 64 + lane] = f2b(sV[lane * 129 + d]);
    }
  }
}

// ---------------- K1: feature maps (MFMA) ----------------
// grid (NBLK, NH, 2), 256 thr = 4 waves; wave w owns q-rows [w*16, w*16+16)
__global__ __launch_bounds__(256) void k_fmap(
    const float* __restrict__ qg, const float* __restrict__ kg,
    const u16* __restrict__ WT,
    u16* __restrict__ fqb, u16* __restrict__ FKT)
{
  __shared__ __align__(16) u16 smem[2 * 64 * 136];
  u16* sX = smem;              // X tile [q][d] pitch 136 ; later aliased as output buf
  u16* sW = smem + 64 * 136;   // WT rows [f][d] pitch 136
  const int lt = blockIdx.x, h = blockIdx.y, isk = blockIdx.z;
  const int tid = threadIdx.x, lane = tid & 63, w = tid >> 6;
  const int quad = lane >> 4, txn = lane & 15;

  // stage X (f32 -> bf16)
  const float* xbase = isk ? (kg + (h >> 2) * HS) : (qg + h * HS);
  const int    xstr  = isk ? (NKV * HS) : (NH * HS);
  for (int idx = tid * 4; idx < 8192; idx += 1024) {
    int r = idx >> 7, c = idx & 127;
    float4 v4 = *(const float4*)(xbase + (size_t)(lt * 64 + r) * xstr + c);
    ushort4 u; u.x = f2b(v4.x); u.y = f2b(v4.y); u.z = f2b(v4.z); u.w = f2b(v4.w);
    *(ushort4*)(sX + r * 136 + c) = u;
  }
  // stage WT rows (bf16, direct)
  const u16* wt = WT + ((size_t)(isk * NH + h)) * 8192;
  for (int i = 0; i < 4; ++i) {
    int ch = tid + i * 256;              // 1024 chunks of 8
    int row = ch >> 4, d8 = (ch & 15) * 8;
    *(uint4*)(sW + row * 136 + d8) = *(const uint4*)(wt + row * 128 + d8);
  }
  __syncthreads();

  // z = X·W^T : C[q][f], m-tile = wave, 4 n-tiles, K=128
  const int arow = w * 16 + txn;
  const f32x4 vzero = {0.f, 0.f, 0.f, 0.f};
  f32x4 zt[4] = {vzero, vzero, vzero, vzero};
#pragma unroll
  for (int ks = 0; ks < 4; ++ks) {
    bf16x8 a = *(const bf16x8*)(sX + arow * 136 + ks * 32 + quad * 8);
#pragma unroll
    for (int nt = 0; nt < 4; ++nt) {
      bf16x8 bb = *(const bf16x8*)(sW + (nt * 16 + txn) * 136 + ks * 32 + quad * 8);
      zt[nt] = __builtin_amdgcn_mfma_f32_16x16x32_bf16(a, bb, zt[nt], 0, 0, 0);
    }
  }

  // dual softmax over 64 features per q-row (row = quad*4+r in wave's m-tile)
  float E1[4][4], E2[4][4];   // [r][nt]
#pragma unroll
  for (int r = 0; r < 4; ++r) {
    float zv[4];
    float mx = -1e30f, mn = 1e30f;
#pragma unroll
    for (int nt = 0; nt < 4; ++nt) {
      zv[nt] = zt[nt][r];
      mx = fmaxf(mx, zv[nt]); mn = fminf(mn, zv[nt]);
    }
#pragma unroll
    for (int o = 1; o < 16; o <<= 1) {
      mx = fmaxf(mx, __shfl_xor(mx, o));
      mn = fminf(mn, __shfl_xor(mn, o));
    }
    float e1[4], e2[4], s1 = 0.f, s2 = 0.f;
#pragma unroll
    for (int nt = 0; nt < 4; ++nt) {
      e1[nt] = __expf(zv[nt] - mx); s1 += e1[nt];
      e2[nt] = __expf(mn - zv[nt]); s2 += e2[nt];
    }
#pragma unroll
    for (int o = 1; o < 16; o <<= 1) { s1 += __shfl_xor(s1, o); s2 += __shfl_xor(s2, o); }
    float r1 = 1.f / s1, r2 = 1.f / s2;
#pragma unroll
    for (int nt = 0; nt < 4; ++nt) {
      E1[r][nt] = fmaxf(e1[nt] * r1, EPSF);
      E2[r][nt] = fmaxf(e2[nt] * r2, EPSF);
    }
  }

  __syncthreads();   // all mfma LDS reads done; safe to alias sX as output

  if (!isk) {
    // fqb row-major [q][128 f] via LDS pitch 136
#pragma unroll
    for (int r = 0; r < 4; ++r) {
      int row = w * 16 + quad * 4 + r;
#pragma unroll
      for (int nt = 0; nt < 4; ++nt) {
        sX[row * 136 + nt * 16 + txn]      = f2b(E1[r][nt]);
        sX[row * 136 + 64 + nt * 16 + txn] = f2b(E2[r][nt]);
      }
    }
    __syncthreads();
    u16* ob = fqb + ((size_t)(h * NBLK + lt)) * 8192;
    for (int i = 0; i < 4; ++i) {
      int ch = tid + i * 256;
      int row = ch >> 4, f8 = (ch & 15) * 8;
      *(uint4*)(ob + row * 128 + f8) = *(const uint4*)(sX + row * 136 + f8);
    }
  } else {
    // FKT transposed [f][j] via LDS pitch 68
#pragma unroll
    for (int r = 0; r < 4; ++r) {
      int j = w * 16 + quad * 4 + r;
#pragma unroll
      for (int nt = 0; nt < 4; ++nt) {
        sX[(nt * 16 + txn) * 68 + j]        = f2b(E1[r][nt]);
        sX[(nt * 16 + txn + 64) * 68 + j]   = f2b(E2[r][nt]);
      }
    }
    __syncthreads();
    u16* ob = FKT + (size_t)h * 128 * T_SEQ + lt * 64;
    for (int i = 0; i < 8; ++i) {
      int ch = tid + i * 256;              // 2048 chunks of 4
      int row = ch >> 4, j4 = (ch & 15) * 4;
      *(ushort4*)(ob + (size_t)row * T_SEQ + j4) = *(const ushort4*)(sX + row * 68 + j4);
    }
  }
}

// ---------------- K2: fused state + prefix scan (MFMA) ----------------
// grid (8 dchunk, 2 fhalf, NH), 256 thr = 4 waves; wave w owns n-tile w (16 f)
__global__ __launch_bounds__(256) void k_scan(
    const u16* __restrict__ FKT, const u16* __restrict__ VT, u16* __restrict__ ST)
{
  __shared__ __align__(16) u16 sVT[16 * 72];
  __shared__ __align__(16) u16 sFK[64 * 72];
  __shared__ __align__(16) u16 sOne[16 * 72];
  __shared__ __align__(16) u16 sO[16 * 72];
  const int dc = blockIdx.x, fh = blockIdx.y, h = blockIdx.z;
  const int tid = threadIdx.x, lane = tid & 63, w = tid >> 6;
  const int quad = lane >> 4, txn = lane & 15;
  const bool doz = (dc == 0);

  // ones tile for z-row MFMA
  for (int idx = tid * 8; idx < 16 * 72; idx += 2048) {
    ushort4 o4; o4.x = 0x3F80; o4.y = 0x3F80; o4.z = 0x3F80; o4.w = 0x3F80;
    *(ushort4*)(sOne + idx) = o4;
    *(ushort4*)(sOne + idx + 4) = o4;
  }

  const u16* vbase = VT + ((size_t)((h >> 2) * 128 + dc * 16)) * T_SEQ;
  const u16* fbase = FKT + ((size_t)(h * 128 + fh * 64)) * T_SEQ;

  // prefetch b=0
  const int srow = tid >> 4, sj4 = (tid & 15) * 4;
  ushort4 rv, rf[4];
  rv = *(const ushort4*)(vbase + (size_t)srow * T_SEQ + sj4);
#pragma unroll
  for (int i = 0; i < 4; ++i) {
    int ch = tid + i * 256;
    int fr = ch >> 4, fj4 = (ch & 15) * 4;
    rf[i] = *(const ushort4*)(fbase + (size_t)fr * T_SEQ + fj4);
  }

  const f32x4 vzero = {0.f, 0.f, 0.f, 0.f};
  f32x4 acc = vzero, zacc = vzero;

  for (int b = 0; b < NBLK; ++b) {
    __syncthreads();            // prev mfma reads + sO readout done
    *(ushort4*)(sVT + srow * 72 + sj4) = rv;
#pragma unroll
    for (int i = 0; i < 4; ++i) {
      int ch = tid + i * 256;
      int fr = ch >> 4, fj4 = (ch & 15) * 4;
      *(ushort4*)(sFK + fr * 72 + fj4) = rf[i];
    }
    __syncthreads();
    if (b + 1 < NBLK) {         // prefetch next chunk; latency hidden by mfma+writes
      rv = *(const ushort4*)(vbase + (size_t)srow * T_SEQ + (b + 1) * 64 + sj4);
#pragma unroll
      for (int i = 0; i < 4; ++i) {
        int ch = tid + i * 256;
        int fr = ch >> 4, fj4 = (ch & 15) * 4;
        rf[i] = *(const ushort4*)(fbase + (size_t)fr * T_SEQ + (b + 1) * 64 + fj4);
      }
    }
#pragma unroll
    for (int ks = 0; ks < 2; ++ks) {
      bf16x8 a  = *(const bf16x8*)(sVT + txn * 72 + ks * 32 + quad * 8);
      bf16x8 bb = *(const bf16x8*)(sFK + (w * 16 + txn) * 72 + ks * 32 + quad * 8);
      acc = __builtin_amdgcn_mfma_f32_16x16x32_bf16(a, bb, acc, 0, 0, 0);
      if (doz) {
        bf16x8 ao = *(const bf16x8*)(sOne + txn * 72 + ks * 32 + quad * 8);
        zacc = __builtin_amdgcn_mfma_f32_16x16x32_bf16(ao, bb, zacc, 0, 0, 0);
      }
    }
    // cumulative state (bf16) -> sO -> global
#pragma unroll
    for (int r = 0; r < 4; ++r)
      sO[(quad * 4 + r) * 72 + w * 16 + txn] = f2b(acc[r]);
    if (doz && quad == 0)
      ST[(((size_t)(h * NBLK + b)) * 144 + 128) * 128 + fh * 64 + w * 16 + txn] = f2b(zacc[0]);
    __syncthreads();
    *(ushort4*)(ST + (((size_t)(h * NBLK + b)) * 144 + dc * 16 + srow) * 128 + fh * 64 + sj4)
        = *(const ushort4*)(sO + srow * 72 + sj4);
  }
}

// ---------------- K4: main attention (MFMA, 35KB LDS -> 4 blocks/CU) ----------------
// grid (NBLK, NH), 256 threads = 4 waves; wave w owns q-rows [w*16, w*16+16)
__global__ __launch_bounds__(256, 4) void k_main(
    const float* __restrict__ qg, const float* __restrict__ kg,
    const u16* __restrict__ fqb, const u16* __restrict__ ST, const u16* __restrict__ VT,
    const float* __restrict__ wfac, float* __restrict__ out)
{
  __shared__ __align__(16) u16 RA[64 * LDP];   // A-operand: FQ -> Q -> P (K-major rows)
  __shared__ __align__(16) u16 RB[64 * LDP];   // B-operand: S^T lo/hi -> K[B] -> K[B-1] -> V^T lo/hi
  __shared__ __align__(16) u16 sz[128];        // z row of S_cum
  const int B = blockIdx.x, h = blockIdx.y, tid = threadIdx.x;
  const int lane = tid & 63, w = tid >> 6;
  const int quad = lane >> 4, txn = lane & 15;
  const int arow = w * 16 + txn;
  const int koff = quad * 8;

  const f32x4 vzero = {0.f, 0.f, 0.f, 0.f};
  f32x4 y[8];
#pragma unroll
  for (int t = 0; t < 8; ++t) y[t] = vzero;
  float sln[4] = {0.f, 0.f, 0.f, 0.f};
  const bf16x8 bzero = {0, 0, 0, 0, 0, 0, 0, 0};

  // ---- linear part: Y += FQ · S_cum[B-2]  (+ z -> sln via n0-only MFMA) ----
  if (B >= 2) {
    const u16* fsrc = fqb + ((size_t)(h * NBLK + B)) * 8192;
    for (int idx = tid * 4; idx < 8192; idx += 1024) {
      int r = idx >> 7, c = idx & 127;
      *(ushort4*)(RA + r * LDP + c) = *(const ushort4*)(fsrc + idx);
    }
    const u16* ssrc = ST + ((size_t)(h * NBLK + (B - 2))) * 18432;
    for (int idx = tid * 4; idx < 8192; idx += 1024) {      // S^T d-rows 0..63
      int r = idx >> 7, c = idx & 127;
      *(ushort4*)(RB + r * LDP + c) = *(const ushort4*)(ssrc + idx);
    }
    if (tid < 32) *(ushort4*)(sz + tid * 4) = *(const ushort4*)(ssrc + 16384 + tid * 4);
    __syncthreads();
    f32x4 yz = vzero;
#pragma unroll
    for (int ks = 0; ks < 4; ++ks) {
      bf16x8 a = *(const bf16x8*)(RA + arow * LDP + ks * 32 + koff);
#pragma unroll
      for (int t = 0; t < 4; ++t) {
        bf16x8 bb = *(const bf16x8*)(RB + (t * 16 + txn) * LDP + ks * 32 + koff);
        y[t] = __builtin_amdgcn_mfma_f32_16x16x32_bf16(a, bb, y[t], 0, 0, 0);
      }
      bf16x8 bz = (txn == 0) ? *(const bf16x8*)(sz + ks * 32 + koff) : bzero;
      yz = __builtin_amdgcn_mfma_f32_16x16x32_bf16(a, bz, yz, 0, 0, 0);
    }
    __syncthreads();
    for (int idx = tid * 4; idx < 8192; idx += 1024) {      // S^T d-rows 64..127
      int r = idx >> 7, c = idx & 127;
      *(ushort4*)(RB + r * LDP + c) = *(const ushort4*)(ssrc + 8192 + idx);
    }
    __syncthreads();
#pragma unroll
    for (int ks = 0; ks < 4; ++ks) {
      bf16x8 a = *(const bf16x8*)(RA + arow * LDP + ks * 32 + koff);
#pragma unroll
      for (int t = 4; t < 8; ++t) {
        bf16x8 bb = *(const bf16x8*)(RB + (t * 16 + txn - 64) * LDP + ks * 32 + koff);
        y[t] = __builtin_amdgcn_mfma_f32_16x16x32_bf16(a, bb, y[t], 0, 0, 0);
      }
    }
#pragma unroll
    for (int r = 0; r < 4; ++r) sln[r] = __shfl(yz[r], lane & 48);  // n==0 lane of own quad
    __syncthreads();   // done reading RA/RB before cooperative restage
  }

  // ---- stage Q (f32->bf16) into RA, K[B] into RB ----
  const int kb0 = (B >= 1) ? B - 1 : 0;
  {
    const float* qs = qg + (size_t)(B * 64) * (NH * HS) + h * HS;
    for (int idx = tid * 4; idx < 8192; idx += 1024) {
      int r = idx >> 7, c = idx & 127;
      float4 v4 = *(const float4*)(qs + (size_t)r * (NH * HS) + c);
      ushort4 u; u.x = f2b(v4.x); u.y = f2b(v4.y); u.z = f2b(v4.z); u.w = f2b(v4.w);
      *(ushort4*)(RA + r * LDP + c) = u;
    }
    const float* kd = kg + (size_t)(B * 64) * (NKV * HS) + (h >> 2) * HS;
    for (int idx = tid * 4; idx < 8192; idx += 1024) {
      int r = idx >> 7, c = idx & 127;
      float4 v4 = *(const float4*)(kd + (size_t)r * (NKV * HS) + c);
      ushort4 u; u.x = f2b(v4.x); u.y = f2b(v4.y); u.z = f2b(v4.z); u.w = f2b(v4.w);
      *(ushort4*)(RB + r * LDP + c) = u;
    }
  }
  __syncthreads();

  // ---- scores: diagonal block -> s[4..7] ----
  f32x4 s[8];
#pragma unroll
  for (int t = 0; t < 8; ++t) s[t] = vzero;
#pragma unroll
  for (int ks = 0; ks < 4; ++ks) {
    bf16x8 a = *(const bf16x8*)(RA + arow * LDP + ks * 32 + koff);
#pragma unroll
    for (int t = 0; t < 4; ++t) {
      bf16x8 bb = *(const bf16x8*)(RB + (t * 16 + txn) * LDP + ks * 32 + koff);
      s[4 + t] = __builtin_amdgcn_mfma_f32_16x16x32_bf16(a, bb, s[4 + t], 0, 0, 0);
    }
  }

  // ---- scores: previous block -> s[0..3] ----
  if (B >= 1) {
    __syncthreads();
    const float* kd = kg + (size_t)(kb0 * 64) * (NKV * HS) + (h >> 2) * HS;
    for (int idx = tid * 4; idx < 8192; idx += 1024) {
      int r = idx >> 7, c = idx & 127;
      float4 v4 = *(const float4*)(kd + (size_t)r * (NKV * HS) + c);
      ushort4 u; u.x = f2b(v4.x); u.y = f2b(v4.y); u.z = f2b(v4.z); u.w = f2b(v4.w);
      *(ushort4*)(RB + r * LDP + c) = u;
    }
    __syncthreads();
#pragma unroll
    for (int ks = 0; ks < 4; ++ks) {
      bf16x8 a = *(const bf16x8*)(RA + arow * LDP + ks * 32 + koff);
#pragma unroll
      for (int t = 0; t < 4; ++t) {
        bf16x8 bb = *(const bf16x8*)(RB + (t * 16 + txn) * LDP + ks * 32 + koff);
        s[t] = __builtin_amdgcn_mfma_f32_16x16x32_bf16(a, bb, s[t], 0, 0, 0);
      }
    }
  }

  // ---- masked softmax, write P (bf16) into RA rows (wave-private) ----
  float wf = wfac[h];
  wf = 1.f / (1.f + __expf(-wf));
  const float scale = 0.08838834764831845f;
  float ssum[4];
#pragma unroll
  for (int r = 0; r < 4; ++r) {
    const int irow = w * 16 + quad * 4 + r;
    float sv[8];
    float m = -1e30f;
#pragma unroll
    for (int t = 0; t < 8; ++t) {
      float x = s[t][r] * scale;
      bool msk = (t < 4) ? (B == 0) : ((t - 4) * 16 + txn > irow);
      x = msk ? -1e30f : x;
      sv[t] = x;
      m = fmaxf(m, x);
    }
#pragma unroll
    for (int o = 1; o < 16; o <<= 1) m = fmaxf(m, __shfl_xor(m, o));
    float ss = 0.f;
#pragma unroll
    for (int t = 0; t < 8; ++t) {
      float e = (sv[t] > -1e29f) ? wf * __expf(sv[t] - m) : 0.f;
      ss += e;
      RA[irow * LDP + t * 16 + txn] = f2b(e);
    }
#pragma unroll
    for (int o = 1; o < 16; o <<= 1) ss += __shfl_xor(ss, o);
    ssum[r] = ss;
  }
  __syncthreads();   // all waves done reading K in RB before V^T overwrite

  // ---- V^T d-rows 0..63 -> PV t=0..3 ----
  const u16* vts = VT + (size_t)((h >> 2) * 128) * T_SEQ;
  for (int idx = tid * 4; idx < 8192; idx += 1024) {
    int r = idx >> 7, c = idx & 127;        // r = d, c = key slot
    int key = (c < 64) ? (kb0 * 64 + c) : (B * 64 + (c - 64));
    *(ushort4*)(RB + r * LDP + c) = *(const ushort4*)(vts + (size_t)r * T_SEQ + key);
  }
  __syncthreads();
#pragma unroll
  for (int ks = 0; ks < 4; ++ks) {
    if (B == 0 && ks < 2) continue;   // P == 0 on prev-block keys
    bf16x8 a = *(const bf16x8*)(RA + arow * LDP + ks * 32 + koff);
#pragma unroll
    for (int t = 0; t < 4; ++t) {
      bf16x8 bb = *(const bf16x8*)(RB + (t * 16 + txn) * LDP + ks * 32 + koff);
      y[t] = __builtin_amdgcn_mfma_f32_16x16x32_bf16(a, bb, y[t], 0, 0, 0);
    }
  }
  __syncthreads();

  // ---- V^T d-rows 64..127 -> PV t=4..7 ----
  for (int idx = tid * 4; idx < 8192; idx += 1024) {
    int r = idx >> 7, c = idx & 127;
    int key = (c < 64) ? (kb0 * 64 + c) : (B * 64 + (c - 64));
    *(ushort4*)(RB + r * LDP + c) = *(const ushort4*)(vts + (size_t)(r + 64) * T_SEQ + key);
  }
  __syncthreads();
#pragma unroll
  for (int ks = 0; ks < 4; ++ks) {
    if (B == 0 && ks < 2) continue;
    bf16x8 a = *(const bf16x8*)(RA + arow * LDP + ks * 32 + koff);
#pragma unroll
    for (int t = 4; t < 8; ++t) {
      bf16x8 bb = *(const bf16x8*)(RB + (t * 16 + txn - 64) * LDP + ks * 32 + koff);
      y[t] = __builtin_amdgcn_mfma_f32_16x16x32_bf16(a, bb, y[t], 0, 0, 0);
    }
  }

  // ---- epilogue ----
  const size_t obase = ((size_t)h * T_SEQ + B * 64) * HS;
#pragma unroll
  for (int r = 0; r < 4; ++r) {
    float inv = 1.f / (ssum[r] + sln[r]);
    int irow = w * 16 + quad * 4 + r;
#pragma unroll
    for (int t = 0; t < 8; ++t)
      out[obase + (size_t)irow * HS + t * 16 + txn] = y[t][r] * inv;
  }
}

extern "C" void kernel_launch(void* const* d_in, const int* in_sizes, int n_in,
                              void* d_out, int out_size, void* d_ws, size_t ws_size,
                              hipStream_t stream) {
  const float* q    = (const float*)d_in[0];
  const float* k    = (const float*)d_in[1];
  const float* v    = (const float*)d_in[2];
  const float* wq   = (const float*)d_in[3];
  const float* wk   = (const float*)d_in[4];
  const float* wfac = (const float*)d_in[5];
  float* out = (float*)d_out;
  char* wsb = (char*)d_ws;

  u16* fqb = (u16*)(wsb + FQB_OFF);
  u16* FKT = (u16*)(wsb + FKT_OFF);
  u16* ST  = (u16*)(wsb + ST_OFF);
  u16* VT  = (u16*)(wsb + VT_OFF);
  u16* WT  = (u16*)(wsb + WT_OFF);

  k_pre  <<<dim3(320),         256, 0, stream>>>(wq, wk, v, WT, VT);
  k_fmap <<<dim3(NBLK, NH, 2), 256, 0, stream>>>(q, k, WT, fqb, FKT);
  k_scan <<<dim3(8, 2, NH),    256, 0, stream>>>(FKT, VT, ST);
  k_main <<<dim3(NBLK, NH),    256, 0, stream>>>(q, k, fqb, ST, VT, wfac, out);
}